// Round 1
// baseline (170.247 us; speedup 1.0000x reference)
//
#include <hip/hip_runtime.h>
#include <hip/hip_bf16.h>
#include <stdint.h>
#include <stddef.h>

#define NROWS 8192
#define DDIM  512
#define TILE  128
#define BK    64
#define NBLK  (NROWS / TILE)   // 64

static_assert(NBLK == 64, "bj extraction assumes 64 col-blocks");

typedef short bf16x8 __attribute__((ext_vector_type(8)));  // 8 bf16 in 4 VGPRs
typedef float f32x4  __attribute__((ext_vector_type(4)));

// async global->LDS, 16B per lane; LDS dest is wave-uniform base + lane*16
__device__ __forceinline__ void async_copy16(const void* g, void* l) {
    __builtin_amdgcn_global_load_lds(
        (const __attribute__((address_space(1))) uint32_t*)g,
        (__attribute__((address_space(3))) uint32_t*)l,
        16, 0, 0);
}

struct bh4 { __hip_bfloat16 x, y, z, w; };

// -------- normalize rows to unit L2 norm (clamp 1e-8), emit bf16 row-major --------
__global__ __launch_bounds__(256) void normalize_bf16_kernel(
    const float* __restrict__ X, __hip_bfloat16* __restrict__ Y)
{
    const int row  = blockIdx.x * 4 + (threadIdx.x >> 6);
    const int lane = threadIdx.x & 63;
    const float* xr = X + (size_t)row * DDIM;
    float4 v0 = ((const float4*)xr)[lane];        // elems lane*4   .. +3
    float4 v1 = ((const float4*)xr)[lane + 64];   // elems 256+lane*4 .. +3
    float ss = v0.x*v0.x + v0.y*v0.y + v0.z*v0.z + v0.w*v0.w
             + v1.x*v1.x + v1.y*v1.y + v1.z*v1.z + v1.w*v1.w;
    #pragma unroll
    for (int d = 1; d < 64; d <<= 1) ss += __shfl_xor(ss, d);
    const float sc = 1.0f / fmaxf(sqrtf(ss), 1e-8f);
    __hip_bfloat16* yr = Y + (size_t)row * DDIM;
    bh4 o0 = { __float2bfloat16(v0.x*sc), __float2bfloat16(v0.y*sc),
               __float2bfloat16(v0.z*sc), __float2bfloat16(v0.w*sc) };
    bh4 o1 = { __float2bfloat16(v1.x*sc), __float2bfloat16(v1.y*sc),
               __float2bfloat16(v1.z*sc), __float2bfloat16(v1.w*sc) };
    ((bh4*)yr)[lane]      = o0;
    ((bh4*)yr)[lane + 64] = o1;
}

// -------- fused S = cn·enT GEMM + exp + row/col partial sums + diag capture --------
// LDS layout (per operand): row r (0..127), 16B-unit u (0..7 over BK=64 bf16):
//   stored at 16B-slot  r*8 + (u ^ (r&7))   -- XOR swizzle so fragment reads
//   (16 lanes, 128B row stride) spread over all 32 banks.
__global__ __launch_bounds__(256, 2) void gemm_loss_kernel(
    const __hip_bfloat16* __restrict__ A,   // cn [N][D] bf16
    const __hip_bfloat16* __restrict__ B,   // en [N][D] bf16
    const float* __restrict__ temp_p,
    float* __restrict__ rowsum,
    float* __restrict__ colsum,
    float* __restrict__ diagv)
{
    __shared__ __hip_bfloat16 As[TILE * BK];   // 16 KB
    __shared__ __hip_bfloat16 Bs[TILE * BK];   // 16 KB

    const int tid  = threadIdx.x;
    const int lane = tid & 63;
    const int wv   = tid >> 6;          // wave 0..3
    const int wi   = (wv >> 1) * 64;    // wave row offset in tile
    const int wj   = (wv & 1) * 64;     // wave col offset in tile
    const int lcol = lane & 15;
    const int q    = lane >> 4;

    const int bi = blockIdx.x & (NBLK - 1);
    const int bj = blockIdx.x >> 6;
    const int row0 = bi * TILE;
    const int col0 = bj * TILE;

    // staging: wave wv loads rows [wv*32, wv*32+32) of both tiles, 4 chunks of 8 rows
    const int sr = lane >> 3;            // row within 8-row chunk
    const int su = (lane & 7) ^ sr;      // k-unit fetched by this lane (swizzle inverse)
    const __hip_bfloat16* Ag = A + (size_t)(row0 + wv * 32 + sr) * DDIM + su * 8;
    const __hip_bfloat16* Bg = B + (size_t)(col0 + wv * 32 + sr) * DDIM + su * 8;

    f32x4 acc[4][4] = {};

    for (int k0 = 0; k0 < DDIM; k0 += BK) {
        __syncthreads();   // previous K-step's LDS reads done before overwrite
        #pragma unroll
        for (int c = 0; c < 4; ++c) {
            async_copy16(Ag + (size_t)(c * 8) * DDIM + k0, &As[(wv * 32 + c * 8) * BK]);
            async_copy16(Bg + (size_t)(c * 8) * DDIM + k0, &Bs[(wv * 32 + c * 8) * BK]);
        }
        __syncthreads();   // compiler drains vmcnt before s_barrier

        #pragma unroll
        for (int kk = 0; kk < 2; ++kk) {
            bf16x8 af[4], bfr[4];
            const int u = kk * 4 + q;    // this lane's 16B k-unit
            #pragma unroll
            for (int mt = 0; mt < 4; ++mt) {
                const int r = wi + mt * 16 + lcol;
                const int s = u ^ (r & 7);
                af[mt] = *(const bf16x8*)&As[r * BK + s * 8];
            }
            #pragma unroll
            for (int nt = 0; nt < 4; ++nt) {
                const int r = wj + nt * 16 + lcol;
                const int s = u ^ (r & 7);
                bfr[nt] = *(const bf16x8*)&Bs[r * BK + s * 8];
            }
            #pragma unroll
            for (int mt = 0; mt < 4; ++mt)
                #pragma unroll
                for (int nt = 0; nt < 4; ++nt)
                    acc[mt][nt] = __builtin_amdgcn_mfma_f32_16x16x32_bf16(
                        af[mt], bfr[nt], acc[mt][nt], 0, 0, 0);
        }
    }

    // ---- epilogue: e = exp(s - M), M = 1/T (max possible), diag excluded ----
    const float invT = 1.0f / temp_p[0];
    const float M = invT;

    float rs[4][4];   // per-lane row partials [mt][reg]
    float cs[4];      // per-lane col partials [nt]
    #pragma unroll
    for (int mt = 0; mt < 4; ++mt)
        #pragma unroll
        for (int r = 0; r < 4; ++r) rs[mt][r] = 0.f;
    #pragma unroll
    for (int nt = 0; nt < 4; ++nt) cs[nt] = 0.f;

    #pragma unroll
    for (int mt = 0; mt < 4; ++mt) {
        #pragma unroll
        for (int nt = 0; nt < 4; ++nt) {
            #pragma unroll
            for (int r = 0; r < 4; ++r) {
                // C/D layout: col = lane&15, row = quad*4 + reg  [m89/m91]
                const int gi = row0 + wi + mt * 16 + q * 4 + r;
                const int gj = col0 + wj + nt * 16 + lcol;
                const float sv = acc[mt][nt][r] * invT;
                float e;
                if (gi == gj) { diagv[gi] = sv; e = 0.f; }
                else          { e = __expf(sv - M); }
                rs[mt][r] += e;
                cs[nt]    += e;
            }
        }
    }

    // row sums: reduce across the 16 columns (lane bits 0..3)
    #pragma unroll
    for (int d = 1; d < 16; d <<= 1)
        #pragma unroll
        for (int mt = 0; mt < 4; ++mt)
            #pragma unroll
            for (int r = 0; r < 4; ++r)
                rs[mt][r] += __shfl_xor(rs[mt][r], d);

    // col sums: reduce across the 4 quads (lane bits 4..5)
    #pragma unroll
    for (int d = 16; d < 64; d <<= 1)
        #pragma unroll
        for (int nt = 0; nt < 4; ++nt)
            cs[nt] += __shfl_xor(cs[nt], d);

    if (lcol == 0) {
        #pragma unroll
        for (int mt = 0; mt < 4; ++mt)
            #pragma unroll
            for (int r = 0; r < 4; ++r)
                atomicAdd(&rowsum[row0 + wi + mt * 16 + q * 4 + r], rs[mt][r]);
    }
    if (q == 0) {
        #pragma unroll
        for (int nt = 0; nt < 4; ++nt)
            atomicAdd(&colsum[col0 + wj + nt * 16 + lcol], cs[nt]);
    }
}

// -------- final scalar: loss = mean_i( 2M + log(rowsum_i) + log(colsum_i) - 2*diag_i ) ----
__global__ __launch_bounds__(256) void finalize_kernel(
    const float* __restrict__ rowsum, const float* __restrict__ colsum,
    const float* __restrict__ diagv,  const float* __restrict__ temp_p,
    float* __restrict__ out)
{
    __shared__ float red[4];
    const float M = 1.0f / temp_p[0];
    float s = 0.f;
    for (int i = threadIdx.x; i < NROWS; i += 256)
        s += 2.f * M + logf(rowsum[i]) + logf(colsum[i]) - 2.f * diagv[i];
    #pragma unroll
    for (int d = 1; d < 64; d <<= 1) s += __shfl_xor(s, d);
    if ((threadIdx.x & 63) == 0) red[threadIdx.x >> 6] = s;
    __syncthreads();
    if (threadIdx.x == 0)
        out[0] = (red[0] + red[1] + red[2] + red[3]) / (float)NROWS;
}

extern "C" void kernel_launch(void* const* d_in, const int* in_sizes, int n_in,
                              void* d_out, int out_size, void* d_ws, size_t ws_size,
                              hipStream_t stream) {
    (void)in_sizes; (void)n_in; (void)out_size; (void)ws_size;
    const float* cxr    = (const float*)d_in[0];
    const float* ehr    = (const float*)d_in[1];
    const float* temp_p = (const float*)d_in[2];
    float* out = (float*)d_out;

    // workspace: rowsum[N] | colsum[N] | diag[N] | cn bf16 [N*D] | en bf16 [N*D]  (~16.9 MB)
    float* rowsum = (float*)d_ws;
    float* colsum = rowsum + NROWS;
    float* diagv  = colsum + NROWS;
    __hip_bfloat16* cn = (__hip_bfloat16*)(diagv + NROWS);
    __hip_bfloat16* en = cn + (size_t)NROWS * DDIM;

    hipMemsetAsync(rowsum, 0, 2 * NROWS * sizeof(float), stream);
    normalize_bf16_kernel<<<NROWS / 4, 256, 0, stream>>>(cxr, cn);
    normalize_bf16_kernel<<<NROWS / 4, 256, 0, stream>>>(ehr, en);
    gemm_loss_kernel<<<NBLK * NBLK, 256, 0, stream>>>(cn, en, temp_p, rowsum, colsum, diagv);
    finalize_kernel<<<1, 256, 0, stream>>>(rowsum, colsum, diagv, temp_p, out);
}

// Round 2
// 164.513 us; speedup vs baseline: 1.0349x; 1.0349x over previous
//
#include <hip/hip_runtime.h>
#include <hip/hip_bf16.h>
#include <stdint.h>
#include <stddef.h>

#define NROWS 8192
#define DDIM  512
#define TILE  128
#define BK    64
#define NBLK  (NROWS / TILE)   // 64

static_assert(NBLK == 64, "bj extraction assumes 64 col-blocks");

typedef short bf16x8 __attribute__((ext_vector_type(8)));  // 8 bf16 in 4 VGPRs
typedef float f32x4  __attribute__((ext_vector_type(4)));

// async global->LDS, 16B per lane; LDS dest is wave-uniform base + lane*16
__device__ __forceinline__ void async_copy16(const void* g, void* l) {
    __builtin_amdgcn_global_load_lds(
        (const __attribute__((address_space(1))) uint32_t*)g,
        (__attribute__((address_space(3))) uint32_t*)l,
        16, 0, 0);
}

struct bh4 { __hip_bfloat16 x, y, z, w; };

// -------- prep: zero accumulators + normalize both matrices to bf16 --------
// grid = 4096 blocks: blocks [0,2048) handle cxr->cn, [2048,4096) handle ehr->en.
// blocks [0,64) additionally zero rowsum/colsum (64*256 = 16384 floats = 2N);
// block 0 thread 0 zeroes out[0] (harness re-poisons d_out each call).
__global__ __launch_bounds__(256) void prep_kernel(
    const float* __restrict__ CXR, const float* __restrict__ EHR,
    __hip_bfloat16* __restrict__ CN, __hip_bfloat16* __restrict__ EN,
    float* __restrict__ rowsum /* colsum follows contiguously */,
    float* __restrict__ out)
{
    if (blockIdx.x < 64) {
        rowsum[blockIdx.x * 256 + threadIdx.x] = 0.f;
        if (blockIdx.x == 0 && threadIdx.x == 0) out[0] = 0.f;
    }
    const int half = (blockIdx.x >= 2048);
    const float* X = half ? EHR : CXR;
    __hip_bfloat16* Y = half ? EN : CN;
    const int row  = (blockIdx.x & 2047) * 4 + (threadIdx.x >> 6);
    const int lane = threadIdx.x & 63;
    const float* xr = X + (size_t)row * DDIM;
    float4 v0 = ((const float4*)xr)[lane];        // elems lane*4   .. +3
    float4 v1 = ((const float4*)xr)[lane + 64];   // elems 256+lane*4 .. +3
    float ss = v0.x*v0.x + v0.y*v0.y + v0.z*v0.z + v0.w*v0.w
             + v1.x*v1.x + v1.y*v1.y + v1.z*v1.z + v1.w*v1.w;
    #pragma unroll
    for (int d = 1; d < 64; d <<= 1) ss += __shfl_xor(ss, d);
    const float sc = 1.0f / fmaxf(sqrtf(ss), 1e-8f);
    __hip_bfloat16* yr = Y + (size_t)row * DDIM;
    bh4 o0 = { __float2bfloat16(v0.x*sc), __float2bfloat16(v0.y*sc),
               __float2bfloat16(v0.z*sc), __float2bfloat16(v0.w*sc) };
    bh4 o1 = { __float2bfloat16(v1.x*sc), __float2bfloat16(v1.y*sc),
               __float2bfloat16(v1.z*sc), __float2bfloat16(v1.w*sc) };
    ((bh4*)yr)[lane]      = o0;
    ((bh4*)yr)[lane + 64] = o1;
}

// -------- fused S = cn·enT GEMM + exp + row/col partial sums + diag capture --------
// LDS layout (per operand): row r (0..127), 16B-unit u (0..7 over BK=64 bf16):
//   stored at 16B-slot  r*8 + (u ^ (r&7))   -- XOR swizzle so fragment reads
//   (16 lanes, 128B row stride) spread over all 32 banks.
__global__ __launch_bounds__(256, 2) void gemm_loss_kernel(
    const __hip_bfloat16* __restrict__ A,   // cn [N][D] bf16
    const __hip_bfloat16* __restrict__ B,   // en [N][D] bf16
    const float* __restrict__ temp_p,
    float* __restrict__ rowsum,
    float* __restrict__ colsum,
    float* __restrict__ diagv)
{
    __shared__ __hip_bfloat16 As[TILE * BK];   // 16 KB
    __shared__ __hip_bfloat16 Bs[TILE * BK];   // 16 KB

    const int tid  = threadIdx.x;
    const int lane = tid & 63;
    const int wv   = tid >> 6;          // wave 0..3
    const int wi   = (wv >> 1) * 64;    // wave row offset in tile
    const int wj   = (wv & 1) * 64;     // wave col offset in tile
    const int lcol = lane & 15;
    const int q    = lane >> 4;

    const int bi = blockIdx.x & (NBLK - 1);
    const int bj = blockIdx.x >> 6;
    const int row0 = bi * TILE;
    const int col0 = bj * TILE;

    // staging: wave wv loads rows [wv*32, wv*32+32) of both tiles, 4 chunks of 8 rows
    const int sr = lane >> 3;            // row within 8-row chunk
    const int su = (lane & 7) ^ sr;      // k-unit fetched by this lane (swizzle inverse)
    const __hip_bfloat16* Ag = A + (size_t)(row0 + wv * 32 + sr) * DDIM + su * 8;
    const __hip_bfloat16* Bg = B + (size_t)(col0 + wv * 32 + sr) * DDIM + su * 8;

    f32x4 acc[4][4] = {};

    for (int k0 = 0; k0 < DDIM; k0 += BK) {
        __syncthreads();   // previous K-step's LDS reads done before overwrite
        #pragma unroll
        for (int c = 0; c < 4; ++c) {
            async_copy16(Ag + (size_t)(c * 8) * DDIM + k0, &As[(wv * 32 + c * 8) * BK]);
            async_copy16(Bg + (size_t)(c * 8) * DDIM + k0, &Bs[(wv * 32 + c * 8) * BK]);
        }
        __syncthreads();   // compiler drains vmcnt before s_barrier

        #pragma unroll
        for (int kk = 0; kk < 2; ++kk) {
            bf16x8 af[4], bfr[4];
            const int u = kk * 4 + q;    // this lane's 16B k-unit
            #pragma unroll
            for (int mt = 0; mt < 4; ++mt) {
                const int r = wi + mt * 16 + lcol;
                const int s = u ^ (r & 7);
                af[mt] = *(const bf16x8*)&As[r * BK + s * 8];
            }
            #pragma unroll
            for (int nt = 0; nt < 4; ++nt) {
                const int r = wj + nt * 16 + lcol;
                const int s = u ^ (r & 7);
                bfr[nt] = *(const bf16x8*)&Bs[r * BK + s * 8];
            }
            #pragma unroll
            for (int mt = 0; mt < 4; ++mt)
                #pragma unroll
                for (int nt = 0; nt < 4; ++nt)
                    acc[mt][nt] = __builtin_amdgcn_mfma_f32_16x16x32_bf16(
                        af[mt], bfr[nt], acc[mt][nt], 0, 0, 0);
        }
    }

    // ---- epilogue: e = exp(s - M), M = 1/T (max possible), diag excluded ----
    const float invT = 1.0f / temp_p[0];
    const float M = invT;

    float rs[4][4];   // per-lane row partials [mt][reg]
    float cs[4];      // per-lane col partials [nt]
    #pragma unroll
    for (int mt = 0; mt < 4; ++mt)
        #pragma unroll
        for (int r = 0; r < 4; ++r) rs[mt][r] = 0.f;
    #pragma unroll
    for (int nt = 0; nt < 4; ++nt) cs[nt] = 0.f;

    #pragma unroll
    for (int mt = 0; mt < 4; ++mt) {
        #pragma unroll
        for (int nt = 0; nt < 4; ++nt) {
            #pragma unroll
            for (int r = 0; r < 4; ++r) {
                // C/D layout: col = lane&15, row = quad*4 + reg  [m89/m91]
                const int gi = row0 + wi + mt * 16 + q * 4 + r;
                const int gj = col0 + wj + nt * 16 + lcol;
                const float sv = acc[mt][nt][r] * invT;
                float e;
                if (gi == gj) { diagv[gi] = sv; e = 0.f; }
                else          { e = __expf(sv - M); }
                rs[mt][r] += e;
                cs[nt]    += e;
            }
        }
    }

    // row sums: reduce across the 16 columns (lane bits 0..3)
    #pragma unroll
    for (int d = 1; d < 16; d <<= 1)
        #pragma unroll
        for (int mt = 0; mt < 4; ++mt)
            #pragma unroll
            for (int r = 0; r < 4; ++r)
                rs[mt][r] += __shfl_xor(rs[mt][r], d);

    // col sums: reduce across the 4 quads (lane bits 4..5)
    #pragma unroll
    for (int d = 16; d < 64; d <<= 1)
        #pragma unroll
        for (int nt = 0; nt < 4; ++nt)
            cs[nt] += __shfl_xor(cs[nt], d);

    if (lcol == 0) {
        #pragma unroll
        for (int mt = 0; mt < 4; ++mt)
            #pragma unroll
            for (int r = 0; r < 4; ++r)
                atomicAdd(&rowsum[row0 + wi + mt * 16 + q * 4 + r], rs[mt][r]);
    }
    if (q == 0) {
        #pragma unroll
        for (int nt = 0; nt < 4; ++nt)
            atomicAdd(&colsum[col0 + wj + nt * 16 + lcol], cs[nt]);
    }
}

// -------- final scalar: loss = mean_i( 2M + log(rowsum_i) + log(colsum_i) - 2*diag_i ) ----
// 32 blocks x 256 threads, one i per thread; atomicAdd partial means into out[0]
// (out[0] pre-zeroed by prep_kernel; cross-dispatch ordering on the same stream).
__global__ __launch_bounds__(256) void finalize_kernel(
    const float* __restrict__ rowsum, const float* __restrict__ colsum,
    const float* __restrict__ diagv,  const float* __restrict__ temp_p,
    float* __restrict__ out)
{
    __shared__ float red[4];
    const float M = 1.0f / temp_p[0];
    const int i = blockIdx.x * 256 + threadIdx.x;
    float s = 2.f * M + logf(rowsum[i]) + logf(colsum[i]) - 2.f * diagv[i];
    #pragma unroll
    for (int d = 1; d < 64; d <<= 1) s += __shfl_xor(s, d);
    if ((threadIdx.x & 63) == 0) red[threadIdx.x >> 6] = s;
    __syncthreads();
    if (threadIdx.x == 0)
        atomicAdd(out, (red[0] + red[1] + red[2] + red[3]) / (float)NROWS);
}

extern "C" void kernel_launch(void* const* d_in, const int* in_sizes, int n_in,
                              void* d_out, int out_size, void* d_ws, size_t ws_size,
                              hipStream_t stream) {
    (void)in_sizes; (void)n_in; (void)out_size; (void)ws_size;
    const float* cxr    = (const float*)d_in[0];
    const float* ehr    = (const float*)d_in[1];
    const float* temp_p = (const float*)d_in[2];
    float* out = (float*)d_out;

    // workspace: rowsum[N] | colsum[N] | diag[N] | cn bf16 [N*D] | en bf16 [N*D]  (~16.9 MB)
    float* rowsum = (float*)d_ws;
    float* colsum = rowsum + NROWS;
    float* diagv  = colsum + NROWS;
    __hip_bfloat16* cn = (__hip_bfloat16*)(diagv + NROWS);
    __hip_bfloat16* en = cn + (size_t)NROWS * DDIM;

    prep_kernel<<<4096, 256, 0, stream>>>(cxr, ehr, cn, en, rowsum, out);
    gemm_loss_kernel<<<NBLK * NBLK, 256, 0, stream>>>(cn, en, temp_p, rowsum, colsum, diagv);
    finalize_kernel<<<NROWS / 256, 256, 0, stream>>>(rowsum, colsum, diagv, temp_p, out);
}